// Round 5
// baseline (5747.773 us; speedup 1.0000x reference)
//
#include <hip/hip_runtime.h>
#include <hip/hip_cooperative_groups.h>

namespace cg = cooperative_groups;

static constexpr int E0 = 160000;   // level-0 edges
static constexpr int NL0 = 20000;   // nodes level 0
static constexpr int NL1 = 6912;    // 4 * 12^3   (voxel 20)
static constexpr int NL2 = 2048;    // 4 * 8^3    (voxel 30)
static constexpr int NL3 = 500;     // 4 * 5^3    (voxel 50)

typedef short bf16x8 __attribute__((ext_vector_type(8)));
typedef float f32x4 __attribute__((ext_vector_type(4)));

// ---------- helpers ----------
__device__ __forceinline__ unsigned f2ord(float f) {
  unsigned u = __float_as_uint(f);
  return (u & 0x80000000u) ? ~u : (u | 0x80000000u);
}
__device__ __forceinline__ float ord2f(unsigned u) {
  unsigned v = (u & 0x80000000u) ? (u & 0x7fffffffu) : ~u;
  return __uint_as_float(v);
}
__device__ __forceinline__ float eluf(float x) { return x > 0.f ? x : expm1f(x); }
__device__ __forceinline__ void basis8(float u0, float u1, float u2, float* w) {
  float a0 = 1.f - u0, a1 = 1.f - u1, a2 = 1.f - u2;
  w[0] = a0*a1*a2; w[1] = a0*a1*u2; w[2] = a0*u1*a2; w[3] = a0*u1*u2;
  w[4] = u0*a1*a2; w[5] = u0*a1*u2; w[6] = u0*u1*a2; w[7] = u0*u1*u2;
}
__device__ __forceinline__ unsigned short f2b(float f) {  // fp32 -> bf16 RNE
  unsigned u = __float_as_uint(f);
  return (unsigned short)((u + 0x7fffu + ((u >> 16) & 1u)) >> 16);
}
__device__ __forceinline__ float b2f(unsigned short h) {
  return __uint_as_float(((unsigned)h) << 16);
}
__device__ __forceinline__ int clampi(int v, int lo, int hi) {
  return v < lo ? lo : (v > hi ? hi : v);
}
__device__ __forceinline__ void blockMaxTo(float v, float* sred, float* dst) {
  #pragma unroll
  for (int off = 32; off; off >>= 1) v = fmaxf(v, __shfl_down(v, off, 64));
  int ln = threadIdx.x & 63, wv = threadIdx.x >> 6;
  __syncthreads();
  if (ln == 0) sred[wv] = v;
  __syncthreads();
  if (threadIdx.x == 0)
    atomicMax((unsigned*)dst,
              __float_as_uint(fmaxf(fmaxf(sred[0], sred[1]), fmaxf(sred[2], sred[3]))));
  __syncthreads();
}

// ---------- MFMA 64x64 tile core (bf16 hi/lo 3-pass) ----------
__device__ __forceinline__ void mfma_tile(const unsigned short* __restrict__ Ah,
    const unsigned short* __restrict__ Al, const unsigned short* __restrict__ Bh,
    const unsigned short* __restrict__ Bl, int M, long K, int m0, int n0,
    int kbeg, int ksl, char* smem, f32x4* acc) {
  auto Ash = (unsigned short (*)[40])(smem);
  auto Asl = (unsigned short (*)[40])(smem + 5120);
  auto Bsh = (unsigned short (*)[40])(smem + 10240);
  auto Bsl = (unsigned short (*)[40])(smem + 15360);
  int t = threadIdx.x;
  int r = t >> 2, sg = (t & 3) * 8;
  int w = t >> 6, lane = t & 63;
  int ar = (w << 4) + (lane & 15), kq = (lane >> 4) << 3;
  for (int kt = 0; kt < ksl; kt += 32) {
    bf16x8 va = {}, vl = {};
    if (m0 + r < M) {
      long ga = (long)(m0 + r) * K + kbeg + kt + sg;
      va = *(const bf16x8*)&Ah[ga];
      vl = *(const bf16x8*)&Al[ga];
    }
    *(bf16x8*)&Ash[r][sg] = va;
    *(bf16x8*)&Asl[r][sg] = vl;
    long gb = (long)(n0 + r) * K + kbeg + kt + sg;
    *(bf16x8*)&Bsh[r][sg] = *(const bf16x8*)&Bh[gb];
    *(bf16x8*)&Bsl[r][sg] = *(const bf16x8*)&Bl[gb];
    __syncthreads();
    bf16x8 ah = *(const bf16x8*)&Ash[ar][kq];
    bf16x8 al = *(const bf16x8*)&Asl[ar][kq];
    #pragma unroll
    for (int nt = 0; nt < 4; nt++) {
      int br = (nt << 4) + (lane & 15);
      bf16x8 bh = *(const bf16x8*)&Bsh[br][kq];
      bf16x8 bl = *(const bf16x8*)&Bsl[br][kq];
      acc[nt] = __builtin_amdgcn_mfma_f32_16x16x32_bf16(al, bh, acc[nt], 0, 0, 0);
      acc[nt] = __builtin_amdgcn_mfma_f32_16x16x32_bf16(ah, bl, acc[nt], 0, 0, 0);
      acc[nt] = __builtin_amdgcn_mfma_f32_16x16x32_bf16(ah, bh, acc[nt], 0, 0, 0);
    }
    __syncthreads();
  }
}

struct KParams {
  const float *x0, *pos0; const int *src0, *dst0;
  const float *W1, *Wr1, *b1, *W2, *Wr2, *b2, *W3, *Wr3, *b3, *W4, *Wr4, *b4;
  const float *fw1, *fb1, *fw2, *fb2;
  float* out;
  int *src1, *dst1, *src2, *dst2, *src3, *dst3;
  float *x1p, *x2p, *x3p, *pos1, *pos2, *pos3;
  unsigned char *val1, *val2, *val3;
  unsigned short *ysh, *ysl;
  float* wc1;
  unsigned short *w2h, *w2l, *w3h, *w3l, *w4h, *w4l;
  float* Cp;
  int *nid, *rowbeg, *rowlen, *cursor, *esrc;
  float *h, *cnt, *possum; unsigned *pord, *xg;
  int* degi; unsigned* bitmap; float* mbuf; int *ecnt, *ctr;
  unsigned* zA; long zAw; unsigned* z0; long z0w;
};

extern "C" __global__ void __launch_bounds__(256, 4) mega(KParams p) {
  cg::grid_group grid = cg::this_grid();
  __shared__ __align__(16) char smem[20608];
  float* sred = (float*)(smem + 20480);
  const int tid = blockIdx.x * 256 + threadIdx.x;
  const int gsz = gridDim.x * 256;
  const int wgid = blockIdx.x * 4 + (threadIdx.x >> 6);
  const int nwv = gridDim.x * 4;
  const int lane = threadIdx.x & 63;

  // ===== s0: zero accumulator state + weight prep =====
  for (long i = tid; i < p.z0w; i += gsz) p.z0[i] = 0u;
  for (long i = tid; i < p.zAw; i += gsz) p.zA[i] = 0u;
  for (int b = blockIdx.x; b < 378; b += gridDim.x) {
    float (*T)[65] = (float (*)[65])smem;
    const float *W, *Wr; unsigned short *oh, *ol; int K, N, kt, nt;
    if (b < 18)      { W = p.W2; Wr = p.Wr2; oh = p.w2h; ol = p.w2l; K = 576;  N = 128; kt = b / 2; nt = b % 2; }
    else if (b < 90) { int q = b - 18; W = p.W3; Wr = p.Wr3; oh = p.w3h; ol = p.w3l; K = 1152; N = 256; kt = q / 4; nt = q % 4; }
    else             { int q = b - 90; W = p.W4; Wr = p.Wr4; oh = p.w4h; ol = p.w4l; K = 2304; N = 512; kt = q / 8; nt = q % 8; }
    int k0 = kt * 64, n0 = nt * 64, KW = K - K / 9;
    __syncthreads();
    for (int i = threadIdx.x; i < 4096; i += 256) {
      int kk = i >> 6, nn = i & 63, k = k0 + kk;
      T[kk][nn] = (k < KW) ? W[(long)k * N + n0 + nn] : Wr[(long)(k - KW) * N + n0 + nn];
    }
    __syncthreads();
    for (int i = threadIdx.x; i < 4096; i += 256) {
      int nn = i >> 6, kk = i & 63;
      float v = T[kk][nn];
      unsigned short hu = f2b(v), lu = f2b(v - b2f(hu));
      long o = (long)(n0 + nn) * K + k0 + kk;
      oh[o] = hu; ol[o] = lu;
    }
  }
  if (blockIdx.x == 0)
    for (int i = threadIdx.x; i < 576; i += 256)
      p.wc1[i] = (i < 512) ? p.W1[i] : p.Wr1[i - 512];
  grid.sync();

  // ----- reusable phase lambdas -----
  auto allocp = [&](int N, int lvl) {
    for (int n = tid; n < N; n += gsz) {
      int len = p.degi[n];
      int st = atomicAdd(&p.ctr[lvl], len);
      p.rowbeg[n] = st; p.cursor[n] = st; p.rowlen[n] = len; p.degi[n] = 0;
    }
  };
  auto scat = [&](const int* s, const int* d, int n) {
    for (int e = tid; e < n; e += gsz) {
      int q = atomicAdd(&p.cursor[d[e]], 1);
      p.esrc[q] = s[e];
    }
  };
  auto pfin = [&](float* xp, float* posp, unsigned char* vp, int Nn, int Cf) {
    for (long idx = tid; idx < (long)Nn * Cf; idx += gsz) {
      int n = (int)(idx / Cf), o = (int)(idx % Cf);
      float c = p.cnt[n];
      xp[idx] = (c > 0.f) ? ord2f(p.pord[idx]) : 0.f;
      if (o == 0) {
        vp[n] = (c > 0.f) ? 1 : 0;
        float ic = 1.f / fmaxf(c, 1.f);
        posp[n*3]   = p.possum[n*3]   * ic;
        posp[n*3+1] = p.possum[n*3+1] * ic;
        posp[n*3+2] = p.possum[n*3+2] * ic;
      }
    }
  };
  auto pedge = [&](const int* sf, const int* df, int n, int Nn,
                   int* sc_, int* dc_, int* ec_, float* mo) {
    float vmax = 0.f;
    for (int e = tid; e < n; e += gsz) {
      int s2 = p.nid[sf[e]], d2 = p.nid[df[e]];
      if (s2 == d2) continue;
      float ics = 1.f / fmaxf(p.cnt[s2], 1.f), icd = 1.f / fmaxf(p.cnt[d2], 1.f);
      vmax = fmaxf(vmax, fabsf(p.possum[s2*3]   * ics - p.possum[d2*3]   * icd));
      vmax = fmaxf(vmax, fabsf(p.possum[s2*3+1] * ics - p.possum[d2*3+1] * icd));
      vmax = fmaxf(vmax, fabsf(p.possum[s2*3+2] * ics - p.possum[d2*3+2] * icd));
      unsigned key = (unsigned)s2 * (unsigned)Nn + (unsigned)d2;
      unsigned bit = 1u << (key & 31);
      unsigned old = atomicOr(&p.bitmap[key >> 5], bit);
      if (!(old & bit)) {
        int q = atomicAdd(ec_, 1);
        sc_[q] = s2; dc_[q] = d2;
        atomicAdd(&p.degi[d2], 1);
      }
    }
    blockMaxTo(vmax, sred, mo);
  };
  auto gath = [&](const float* pos, const float* x, float mv, int N, int Ci, int nchunk) {
    for (long i = tid; i < p.zAw; i += gsz) p.zA[i] = 0u;   // re-zero pool accum
    float inv = 0.5f / fmaxf(mv, 1e-9f);
    for (int widx = wgid; widx < N * nchunk; widx += nwv) {
      int d = widx / nchunk, ch = widx % nchunk;
      int co = ch * 64 + lane;
      float pd0 = pos[d*3], pd1 = pos[d*3+1], pd2 = pos[d*3+2];
      int beg = p.rowbeg[d], len = p.rowlen[d], end = beg + len;
      float acc[8] = {};
      int scur = (beg < end) ? p.esrc[beg] : 0;
      for (int j = beg; j < end; j++) {
        int s = scur;
        scur = (j + 1 < end) ? p.esrc[j + 1] : 0;
        float u0 = (pos[s*3]   - pd0) * inv + 0.5f;
        float u1 = (pos[s*3+1] - pd1) * inv + 0.5f;
        float u2 = (pos[s*3+2] - pd2) * inv + 0.5f;
        float w[8]; basis8(u0, u1, u2, w);
        float xv = x[(long)s * Ci + co];
        #pragma unroll
        for (int k = 0; k < 8; k++) acc[k] += w[k] * xv;
      }
      float sc = 1.f / fmaxf((float)len, 1.f);
      long row = (long)d * 9 * Ci;
      #pragma unroll
      for (int k = 0; k < 8; k++) {
        float v = acc[k] * sc;
        unsigned short hu = f2b(v);
        p.ysh[row + k * Ci + co] = hu;
        p.ysl[row + k * Ci + co] = f2b(v - b2f(hu));
      }
      float xd = x[(long)d * Ci + co];
      unsigned short hu = f2b(xd);
      p.ysh[row + 8 * Ci + co] = hu;
      p.ysl[row + 8 * Ci + co] = f2b(xd - b2f(hu));
    }
  };
  auto gemmpool = [&](const unsigned short* Bh, const unsigned short* Bl,
                      int M, int N, int K, const float* bias,
                      const float* pos, const unsigned char* valid,
                      int div, float vs, int G, int NC) {
    int nbx = N >> 6, njobs = nbx * (M >> 6);
    for (int job = blockIdx.x; job < njobs; job += gridDim.x) {
      int bx = job % nbx, by = job / nbx;
      int m0 = by * 64, n0 = bx * 64;
      f32x4 acc[4] = {};
      mfma_tile(p.ysh, p.ysl, Bh, Bl, M, K, m0, n0, 0, K, smem, acc);
      int w = threadIdx.x >> 6;
      int row0 = m0 + (w << 4) + ((lane >> 4) << 2);
      int colb = n0 + (lane & 15);
      #pragma unroll
      for (int q = 0; q < 4; q++) {
        int gm = row0 + q;
        float p0 = pos[gm*3], p1 = pos[gm*3+1], p2 = pos[gm*3+2];
        int c0 = clampi((int)floorf(p0 / vs), 0, G - 1);
        int c1 = clampi((int)floorf(p1 / vs), 0, G - 1);
        int c2 = clampi((int)floorf(p2 / vs), 0, G - 1);
        int id = (gm / div) * NC + (c0 * G + c1) * G + c2;
        bool vl = valid[gm] != 0;
        if (bx == 0 && (lane & 15) == 0) {
          p.nid[gm] = id;
          if (vl) {
            atomicAdd(&p.cnt[id], 1.f);
            atomicAdd(&p.possum[id*3], p0);
            atomicAdd(&p.possum[id*3+1], p1);
            atomicAdd(&p.possum[id*3+2], p2);
          }
        }
        if (vl) {
          #pragma unroll
          for (int nt = 0; nt < 4; nt++) {
            int col = colb + nt * 16;
            float v = eluf(acc[nt][q] + bias[col]);
            atomicMax(&p.pord[(long)id * N + col], f2ord(v));
          }
        }
      }
    }
  };

  // ===== s1: level-0 degree + absmax =====
  {
    float v = 0.f;
    for (int e = tid; e < E0; e += gsz) {
      int s = p.src0[e], d = p.dst0[e];
      atomicAdd(&p.degi[d], 1);
      v = fmaxf(v, fabsf(p.pos0[s*3]   - p.pos0[d*3]));
      v = fmaxf(v, fabsf(p.pos0[s*3+1] - p.pos0[d*3+1]));
      v = fmaxf(v, fabsf(p.pos0[s*3+2] - p.pos0[d*3+2]));
    }
    blockMaxTo(v, sred, p.mbuf + 0);
  }
  grid.sync();
  // ===== s2/s3: CSR L0 =====
  allocp(NL0, 0);
  grid.sync();
  scat(p.src0, p.dst0, E0);
  grid.sync();

  // ===== s4: fused layer 1 + pool-1 atomics =====
  {
    float inv = 0.5f / fmaxf(p.mbuf[0], 1e-9f);
    for (int d = wgid; d < NL0; d += nwv) {
      float pd0 = p.pos0[d*3], pd1 = p.pos0[d*3+1], pd2 = p.pos0[d*3+2];
      int beg = p.rowbeg[d], len = p.rowlen[d];
      float acc[8] = {};
      for (int j = beg; j < beg + len; j++) {
        int s = p.esrc[j];
        float u0 = (p.pos0[s*3]   - pd0) * inv + 0.5f;
        float u1 = (p.pos0[s*3+1] - pd1) * inv + 0.5f;
        float u2 = (p.pos0[s*3+2] - pd2) * inv + 0.5f;
        float w[8]; basis8(u0, u1, u2, w);
        float xv = p.x0[s];
        #pragma unroll
        for (int k = 0; k < 8; k++) acc[k] += w[k] * xv;
      }
      float sc = 1.f / fmaxf((float)len, 1.f);
      float v = p.b1[lane] + p.x0[d] * p.wc1[512 + lane];
      #pragma unroll
      for (int k = 0; k < 8; k++) v += acc[k] * sc * p.wc1[k * 64 + lane];
      v = eluf(v);
      int c0 = clampi((int)floorf(pd0 / 20.f), 0, 11);
      int c1 = clampi((int)floorf(pd1 / 20.f), 0, 11);
      int c2 = clampi((int)floorf(pd2 / 20.f), 0, 11);
      int id = (d / 5000) * 1728 + (c0 * 12 + c1) * 12 + c2;
      atomicMax(&p.pord[(long)id * 64 + lane], f2ord(v));
      if (lane == 0) {
        p.nid[d] = id;
        atomicAdd(&p.cnt[id], 1.f);
        atomicAdd(&p.possum[id*3], pd0);
        atomicAdd(&p.possum[id*3+1], pd1);
        atomicAdd(&p.possum[id*3+2], pd2);
      }
    }
  }
  grid.sync();

  // ===== s5: pool-fin L1 + edge coarsen L1 =====
  pfin(p.x1p, p.pos1, p.val1, NL1, 64);
  pedge(p.src0, p.dst0, E0, NL1, p.src1, p.dst1, p.ecnt + 0, p.mbuf + 1);
  grid.sync();
  // ===== s6/s7: CSR L1 (+ clear bitmap region for L2 dedup) =====
  allocp(NL1, 1);
  for (long i = tid; i < (long)NL2 * NL2 / 32; i += gsz) p.bitmap[i] = 0u;
  grid.sync();
  scat(p.src1, p.dst1, p.ecnt[0]);
  grid.sync();

  // ===== s8/s9: layer 2 =====
  gath(p.pos1, p.x1p, p.mbuf[1], NL1, 64, 1);
  grid.sync();
  gemmpool(p.w2h, p.w2l, NL1, 128, 576, p.b2, p.pos1, p.val1, 1728, 30.f, 8, 512);
  grid.sync();
  // ===== s10: pool-fin L2 + edge coarsen L2 =====
  pfin(p.x2p, p.pos2, p.val2, NL2, 128);
  pedge(p.src1, p.dst1, p.ecnt[0], NL2, p.src2, p.dst2, p.ecnt + 1, p.mbuf + 2);
  grid.sync();
  // ===== s11/s12: CSR L2 =====
  allocp(NL2, 2);
  for (long i = tid; i < (long)NL3 * NL3 / 32 + 1; i += gsz) p.bitmap[i] = 0u;
  grid.sync();
  scat(p.src2, p.dst2, p.ecnt[1]);
  grid.sync();

  // ===== s13/s14: layer 3 =====
  gath(p.pos2, p.x2p, p.mbuf[2], NL2, 128, 2);
  grid.sync();
  gemmpool(p.w3h, p.w3l, NL2, 256, 1152, p.b3, p.pos2, p.val2, 512, 50.f, 5, 125);
  grid.sync();
  // ===== s15: pool-fin L3 + edge coarsen L3 =====
  pfin(p.x3p, p.pos3, p.val3, NL3, 256);
  pedge(p.src2, p.dst2, p.ecnt[1], NL3, p.src3, p.dst3, p.ecnt + 2, p.mbuf + 3);
  grid.sync();
  // ===== s16/s17: CSR L3 =====
  allocp(NL3, 3);
  grid.sync();
  scat(p.src3, p.dst3, p.ecnt[2]);
  grid.sync();

  // ===== s18: gather L4 =====
  gath(p.pos3, p.x3p, p.mbuf[3], NL3, 256, 4);
  grid.sync();
  // ===== s19: GEMM L4, split-K z=4 partials =====
  for (int job = blockIdx.x; job < 256; job += gridDim.x) {
    int z = job >> 6, rem = job & 63, bx = rem & 7, by = rem >> 3;
    int m0 = by * 64, n0 = bx * 64;
    f32x4 acc[4] = {};
    mfma_tile(p.ysh, p.ysl, p.w4h, p.w4l, 500, 2304, m0, n0, z * 576, 576, smem, acc);
    float* Co = p.Cp + (long)z * 256000;
    int w = threadIdx.x >> 6;
    int row0 = m0 + (w << 4) + ((lane >> 4) << 2);
    int colb = n0 + (lane & 15);
    #pragma unroll
    for (int nt = 0; nt < 4; nt++)
      #pragma unroll
      for (int q = 0; q < 4; q++) {
        int gm = row0 + q;
        if (gm < 500) Co[(long)gm * 512 + colb + nt * 16] = acc[nt][q];
      }
  }
  grid.sync();
  // ===== s20: reduce partials + bias + ELU + final MaxPoolingX =====
  for (long idx = tid; idx < 256000; idx += gsz) {
    int n = (int)(idx >> 9), o = (int)(idx & 511);
    float s = p.Cp[idx] + p.Cp[idx + 256000] + p.Cp[idx + 512000] + p.Cp[idx + 768000];
    float v = eluf(s + p.b4[o]);
    if (!p.val3[n]) continue;
    float p0 = p.pos3[n*3], p1 = p.pos3[n*3+1], p2 = p.pos3[n*3+2];
    int c0 = clampi((int)floorf(p0 / 80.f), 0, 2);
    int c1 = clampi((int)floorf(p1 / 80.f), 0, 2);
    int c2 = clampi((int)floorf(p2 / 80.f), 0, 2);
    int cl = (n / 125) * 64 + (c0 * 3 + c1) * 3 + c2;
    atomicMax(&p.xg[(long)cl * 512 + o], f2ord(v));
  }
  grid.sync();
  // ===== s21: FC1 (skip 37/64 always-empty cells) =====
  {
    int half = threadIdx.x >> 7, tl = threadIdx.x & 127;
    float* xs = (float*)smem + half * 1024;
    int nslots = gridDim.x * 2;
    for (int base = 0; base < 432; base += nslots) {
      int job = base + blockIdx.x * 2 + half;
      bool act = job < 432;
      int cellhalf = act ? (job >> 3) : 0, jb = act ? (job & 7) : 0;
      int cell = cellhalf >> 1, hf = cellhalf & 1;
      int j = jb * 128 + tl;
      __syncthreads();
      if (act)
        for (int q = tl; q < 1024; q += 128) {
          int b = q >> 8, ci = q & 255;
          unsigned o = p.xg[((b * 64 + cell) << 9) + hf * 256 + ci];
          xs[b * 256 + ci] = (o == 0u) ? 0.f : ord2f(o);
        }
      __syncthreads();
      if (act) {
        float a0 = 0, a1 = 0, a2 = 0, a3 = 0;
        int cbase = cell * 512 + hf * 256;
        for (int ci = 0; ci < 256; ci++) {
          float ww = p.fw1[(long)(cbase + ci) * 1024 + j];
          a0 += xs[ci] * ww;       a1 += xs[256 + ci] * ww;
          a2 += xs[512 + ci] * ww; a3 += xs[768 + ci] * ww;
        }
        atomicAdd(&p.h[j], a0);        atomicAdd(&p.h[1024 + j], a1);
        atomicAdd(&p.h[2048 + j], a2); atomicAdd(&p.h[3072 + j], a3);
      }
    }
  }
  grid.sync();
  // ===== s22: FC2 =====
  for (int bb = blockIdx.x; bb < 4; bb += gridDim.x) {
    float a = 0.f;
    for (int j = threadIdx.x; j < 1024; j += 256)
      a += eluf(p.h[bb * 1024 + j] + p.fb1[j]) * p.fw2[j];
    #pragma unroll
    for (int off = 32; off; off >>= 1) a += __shfl_down(a, off, 64);
    __syncthreads();
    if (lane == 0) sred[threadIdx.x >> 6] = a;
    __syncthreads();
    if (threadIdx.x == 0)
      p.out[bb] = eluf(sred[0] + sred[1] + sred[2] + sred[3] + p.fb2[0]);
  }
}

// =======================================================================
extern "C" void kernel_launch(void* const* d_in, const int* in_sizes, int n_in,
                              void* d_out, int out_size, void* d_ws, size_t ws_size,
                              hipStream_t stream) {
  KParams prm;
  prm.x0   = (const float*)d_in[0];
  prm.pos0 = (const float*)d_in[1];
  const int* ei = (const int*)d_in[2];
  prm.src0 = ei; prm.dst0 = ei + E0;
  prm.W1 = (const float*)d_in[4];  prm.Wr1 = (const float*)d_in[5];  prm.b1 = (const float*)d_in[6];
  prm.W2 = (const float*)d_in[7];  prm.Wr2 = (const float*)d_in[8];  prm.b2 = (const float*)d_in[9];
  prm.W3 = (const float*)d_in[10]; prm.Wr3 = (const float*)d_in[11]; prm.b3 = (const float*)d_in[12];
  prm.W4 = (const float*)d_in[13]; prm.Wr4 = (const float*)d_in[14]; prm.b4 = (const float*)d_in[15];
  prm.fw1 = (const float*)d_in[16]; prm.fb1 = (const float*)d_in[17];
  prm.fw2 = (const float*)d_in[18]; prm.fb2 = (const float*)d_in[19];
  prm.out = (float*)d_out;

  char* ws = (char*)d_ws;
  size_t off = 0;
  auto alloc = [&](size_t bytes) -> void* {
    off = (off + 255) & ~(size_t)255;
    void* q = ws + off; off += bytes; return q;
  };
  prm.src1 = (int*)alloc(E0 * 4); prm.dst1 = (int*)alloc(E0 * 4);
  prm.src2 = (int*)alloc(E0 * 4); prm.dst2 = (int*)alloc(E0 * 4);
  prm.src3 = (int*)alloc(E0 * 4); prm.dst3 = (int*)alloc(E0 * 4);
  prm.x1p = (float*)alloc((size_t)NL1 * 64 * 4);
  prm.x2p = (float*)alloc((size_t)NL2 * 128 * 4);
  prm.x3p = (float*)alloc((size_t)NL3 * 256 * 4);
  prm.pos1 = (float*)alloc(NL1 * 12);
  prm.pos2 = (float*)alloc(NL2 * 12);
  prm.pos3 = (float*)alloc(NL3 * 12);
  prm.val1 = (unsigned char*)alloc(NL1);
  prm.val2 = (unsigned char*)alloc(NL2);
  prm.val3 = (unsigned char*)alloc(NL3);
  prm.ysh = (unsigned short*)alloc((size_t)NL1 * 576 * 2);
  prm.ysl = (unsigned short*)alloc((size_t)NL1 * 576 * 2);
  prm.wc1 = (float*)alloc(576 * 4);
  prm.w2h = (unsigned short*)alloc((size_t)576 * 128 * 2);
  prm.w2l = (unsigned short*)alloc((size_t)576 * 128 * 2);
  prm.w3h = (unsigned short*)alloc((size_t)1152 * 256 * 2);
  prm.w3l = (unsigned short*)alloc((size_t)1152 * 256 * 2);
  prm.w4h = (unsigned short*)alloc((size_t)2304 * 512 * 2);
  prm.w4l = (unsigned short*)alloc((size_t)2304 * 512 * 2);
  prm.Cp  = (float*)alloc((size_t)4 * 256000 * 4);
  prm.nid    = (int*)alloc(NL0 * 4);
  prm.rowbeg = (int*)alloc(NL0 * 4);
  prm.rowlen = (int*)alloc(NL0 * 4);
  prm.cursor = (int*)alloc(NL0 * 4);
  prm.esrc   = (int*)alloc(E0 * 4);
  // zA region: re-zeroed before each pooling level
  char* zA = (char*)alloc(0);
  prm.h      = (float*)alloc(4096 * 4);
  prm.cnt    = (float*)alloc(NL1 * 4);
  prm.possum = (float*)alloc(NL1 * 12);
  prm.pord   = (unsigned*)alloc((size_t)NL1 * 64 * 4);
  char* zAend = (char*)alloc(0);
  // z0 region: zeroed once per call
  char* z0 = (char*)alloc(0);
  prm.degi = (int*)alloc(NL0 * 4);
  size_t bmwords = ((size_t)NL1 * NL1 + 31) / 32;
  prm.bitmap = (unsigned*)alloc(bmwords * 4);
  prm.mbuf = (float*)alloc(64);
  prm.ecnt = (int*)alloc(64);
  prm.ctr  = (int*)alloc(64);
  char* z0end = (char*)alloc(0);
  prm.zA = (unsigned*)zA;   prm.zAw = (long)(zAend - zA) / 4;
  prm.z0 = (unsigned*)z0;   prm.z0w = (long)(z0end - z0) / 4;
  prm.xg = prm.pord + (size_t)NL3 * 256;
  (void)ws_size; (void)in_sizes; (void)n_in; (void)out_size;

  int ncu = 256;
  hipDeviceGetAttribute(&ncu, hipDeviceAttributeMultiprocessorCount, 0);
  int maxb = 0;
  if (hipOccupancyMaxActiveBlocksPerMultiprocessor(&maxb, mega, 256, 0) != hipSuccess || maxb < 1)
    maxb = 1;
  int ngrid = maxb * ncu;
  if (ngrid > 1024) ngrid = 1024;
  void* kp[] = { (void*)&prm };
  hipLaunchCooperativeKernel((const void*)mega, dim3(ngrid), dim3(256), kp, 0, stream);
}

// Round 6
// 427.624 us; speedup vs baseline: 13.4412x; 13.4412x over previous
//
#include <hip/hip_runtime.h>

static constexpr int E0 = 160000;   // level-0 edges
static constexpr int NL0 = 20000;   // nodes level 0
static constexpr int NL1 = 6912;    // 4 * 12^3   (voxel 20)
static constexpr int NL2 = 2048;    // 4 * 8^3    (voxel 30)
static constexpr int NL3 = 500;     // 4 * 5^3    (voxel 50)

typedef short bf16x8 __attribute__((ext_vector_type(8)));
typedef float f32x4 __attribute__((ext_vector_type(4)));

// ---------- helpers ----------
__device__ __forceinline__ unsigned f2ord(float f) {
  unsigned u = __float_as_uint(f);
  return (u & 0x80000000u) ? ~u : (u | 0x80000000u);
}
__device__ __forceinline__ float ord2f(unsigned u) {
  unsigned v = (u & 0x80000000u) ? (u & 0x7fffffffu) : ~u;
  return __uint_as_float(v);
}
__device__ __forceinline__ float eluf(float x) { return x > 0.f ? x : expm1f(x); }
__device__ __forceinline__ void basis8(float u0, float u1, float u2, float* w) {
  float a0 = 1.f - u0, a1 = 1.f - u1, a2 = 1.f - u2;
  w[0] = a0*a1*a2; w[1] = a0*a1*u2; w[2] = a0*u1*a2; w[3] = a0*u1*u2;
  w[4] = u0*a1*a2; w[5] = u0*a1*u2; w[6] = u0*u1*a2; w[7] = u0*u1*u2;
}
__device__ __forceinline__ unsigned short f2b(float f) {  // fp32 -> bf16 RNE
  unsigned u = __float_as_uint(f);
  return (unsigned short)((u + 0x7fffu + ((u >> 16) & 1u)) >> 16);
}
__device__ __forceinline__ float b2f(unsigned short h) {
  return __uint_as_float(((unsigned)h) << 16);
}
__device__ __forceinline__ int clampi(int v, int lo, int hi) {
  return v < lo ? lo : (v > hi ? hi : v);
}

// ---------- MFMA 64x64 tile core (bf16 hi/lo 3-pass) ----------
__device__ __forceinline__ void mfma_tile(const unsigned short* __restrict__ Ah,
    const unsigned short* __restrict__ Al, const unsigned short* __restrict__ Bh,
    const unsigned short* __restrict__ Bl, int M, long K, int m0, int n0,
    int kbeg, int ksl, char* smem, f32x4* acc) {
  auto Ash = (unsigned short (*)[40])(smem);
  auto Asl = (unsigned short (*)[40])(smem + 5120);
  auto Bsh = (unsigned short (*)[40])(smem + 10240);
  auto Bsl = (unsigned short (*)[40])(smem + 15360);
  int t = threadIdx.x;
  int r = t >> 2, sg = (t & 3) * 8;
  int w = t >> 6, lane = t & 63;
  int ar = (w << 4) + (lane & 15), kq = (lane >> 4) << 3;
  for (int kt = 0; kt < ksl; kt += 32) {
    bf16x8 va = {}, vl = {};
    if (m0 + r < M) {
      long ga = (long)(m0 + r) * K + kbeg + kt + sg;
      va = *(const bf16x8*)&Ah[ga];
      vl = *(const bf16x8*)&Al[ga];
    }
    *(bf16x8*)&Ash[r][sg] = va;
    *(bf16x8*)&Asl[r][sg] = vl;
    long gb = (long)(n0 + r) * K + kbeg + kt + sg;
    *(bf16x8*)&Bsh[r][sg] = *(const bf16x8*)&Bh[gb];
    *(bf16x8*)&Bsl[r][sg] = *(const bf16x8*)&Bl[gb];
    __syncthreads();
    bf16x8 ah = *(const bf16x8*)&Ash[ar][kq];
    bf16x8 al = *(const bf16x8*)&Asl[ar][kq];
    #pragma unroll
    for (int nt = 0; nt < 4; nt++) {
      int br = (nt << 4) + (lane & 15);
      bf16x8 bh = *(const bf16x8*)&Bsh[br][kq];
      bf16x8 bl = *(const bf16x8*)&Bsl[br][kq];
      acc[nt] = __builtin_amdgcn_mfma_f32_16x16x32_bf16(al, bh, acc[nt], 0, 0, 0);
      acc[nt] = __builtin_amdgcn_mfma_f32_16x16x32_bf16(ah, bl, acc[nt], 0, 0, 0);
      acc[nt] = __builtin_amdgcn_mfma_f32_16x16x32_bf16(ah, bh, acc[nt], 0, 0, 0);
    }
    __syncthreads();
  }
}

// ---------- k_prep: L0 linked-list build + absmax + weight prep ----------
__global__ __launch_bounds__(256)
void k_prep(const int* __restrict__ src0, const int* __restrict__ dst0,
            const float* __restrict__ pos0, int* __restrict__ head0,
            int* __restrict__ next0, float* __restrict__ mbuf,
            const float* __restrict__ W1, const float* __restrict__ Wr1, float* __restrict__ wc1,
            const float* __restrict__ W2, const float* __restrict__ Wr2,
            const float* __restrict__ W3, const float* __restrict__ Wr3,
            const float* __restrict__ W4, const float* __restrict__ Wr4,
            unsigned short* __restrict__ w2h, unsigned short* __restrict__ w2l,
            unsigned short* __restrict__ w3h, unsigned short* __restrict__ w3l,
            unsigned short* __restrict__ w4h, unsigned short* __restrict__ w4l) {
  __shared__ __align__(16) float T[64][65];
  __shared__ float red[4];
  int tid = blockIdx.x * 256 + threadIdx.x, gsz = gridDim.x * 256;
  float v = 0.f;
  for (int e = tid; e < E0; e += gsz) {
    int s = src0[e], d = dst0[e];
    next0[e] = atomicExch(&head0[d], e + 1);
    v = fmaxf(v, fabsf(pos0[s*3]   - pos0[d*3]));
    v = fmaxf(v, fabsf(pos0[s*3+1] - pos0[d*3+1]));
    v = fmaxf(v, fabsf(pos0[s*3+2] - pos0[d*3+2]));
  }
  #pragma unroll
  for (int off = 32; off; off >>= 1) v = fmaxf(v, __shfl_down(v, off, 64));
  if ((threadIdx.x & 63) == 0) red[threadIdx.x >> 6] = v;
  __syncthreads();
  if (threadIdx.x == 0)
    atomicMax((unsigned*)mbuf,
              __float_as_uint(fmaxf(fmaxf(red[0], red[1]), fmaxf(red[2], red[3]))));
  // weight prep (blocks 0..377)
  for (int b = blockIdx.x; b < 378; b += gridDim.x) {
    const float *W, *Wr; unsigned short *oh, *ol; int K, N, kt, nt;
    if (b < 18)      { W = W2; Wr = Wr2; oh = w2h; ol = w2l; K = 576;  N = 128; kt = b / 2; nt = b % 2; }
    else if (b < 90) { int q = b - 18; W = W3; Wr = Wr3; oh = w3h; ol = w3l; K = 1152; N = 256; kt = q / 4; nt = q % 4; }
    else             { int q = b - 90; W = W4; Wr = Wr4; oh = w4h; ol = w4l; K = 2304; N = 512; kt = q / 8; nt = q % 8; }
    int k0 = kt * 64, n0 = nt * 64, KW = K - K / 9;
    __syncthreads();
    for (int i = threadIdx.x; i < 4096; i += 256) {
      int kk = i >> 6, nn = i & 63, k = k0 + kk;
      T[kk][nn] = (k < KW) ? W[(long)k * N + n0 + nn] : Wr[(long)(k - KW) * N + n0 + nn];
    }
    __syncthreads();
    for (int i = threadIdx.x; i < 4096; i += 256) {
      int nn = i >> 6, kk = i & 63;
      float vv = T[kk][nn];
      unsigned short hu = f2b(vv), lu = f2b(vv - b2f(hu));
      long o = (long)(n0 + nn) * K + k0 + kk;
      oh[o] = hu; ol[o] = lu;
    }
  }
  if (blockIdx.x == 0)
    for (int i = threadIdx.x; i < 576; i += 256)
      wc1[i] = (i < 512) ? W1[i] : Wr1[i - 512];
}

// ---------- k_l1: fused layer-1 conv + pool-1 atomics ----------
__global__ __launch_bounds__(256)
void k_l1(const float* __restrict__ pos0, const float* __restrict__ x0,
          const int* __restrict__ src0, const int* __restrict__ head0,
          const int* __restrict__ next0, const float* __restrict__ mbuf,
          const float* __restrict__ wc1, const float* __restrict__ b1,
          unsigned* __restrict__ pord1, float* __restrict__ cnt1,
          float* __restrict__ possum1, int* __restrict__ nid) {
  int d = blockIdx.x * 4 + (threadIdx.x >> 6);
  int lane = threadIdx.x & 63;
  if (d >= NL0) return;
  float inv = 0.5f / fmaxf(mbuf[0], 1e-9f);
  float pd0 = pos0[d*3], pd1 = pos0[d*3+1], pd2 = pos0[d*3+2];
  float acc[8] = {};
  int len = 0;
  for (int j = head0[d]; j; ) {
    int e = j - 1; j = next0[e];
    int s = src0[e];
    float u0 = (pos0[s*3]   - pd0) * inv + 0.5f;
    float u1 = (pos0[s*3+1] - pd1) * inv + 0.5f;
    float u2 = (pos0[s*3+2] - pd2) * inv + 0.5f;
    float w[8]; basis8(u0, u1, u2, w);
    float xv = x0[s];
    #pragma unroll
    for (int k = 0; k < 8; k++) acc[k] += w[k] * xv;
    len++;
  }
  float sc = 1.f / fmaxf((float)len, 1.f);
  float v = b1[lane] + x0[d] * wc1[512 + lane];
  #pragma unroll
  for (int k = 0; k < 8; k++) v += acc[k] * sc * wc1[k * 64 + lane];
  v = eluf(v);
  int c0 = clampi((int)floorf(pd0 / 20.f), 0, 11);
  int c1 = clampi((int)floorf(pd1 / 20.f), 0, 11);
  int c2 = clampi((int)floorf(pd2 / 20.f), 0, 11);
  int id = (d / 5000) * 1728 + (c0 * 12 + c1) * 12 + c2;
  atomicMax(&pord1[(long)id * 64 + lane], f2ord(v));
  if (lane == 0) {
    nid[d] = id;
    atomicAdd(&cnt1[id], 1.f);
    atomicAdd(&possum1[id*3],   pd0);
    atomicAdd(&possum1[id*3+1], pd1);
    atomicAdd(&possum1[id*3+2], pd2);
  }
}

// ---------- k_pedge: coarsen edges (dedup) + build next-level list + absmax ----------
__global__ __launch_bounds__(256)
void k_pedge(const int* __restrict__ srcf, const int* __restrict__ dstf,
             const int* __restrict__ ecntf, int ecap,
             const int* __restrict__ nid, int Nn, unsigned* __restrict__ bitmap,
             int* __restrict__ srcc, int* __restrict__ dstc, int* __restrict__ nextc,
             int* __restrict__ headc, int* __restrict__ ecntc,
             const float* __restrict__ possum, const float* __restrict__ cnt,
             float* __restrict__ mo) {
  __shared__ float red[4];
  int n = ecntf ? *ecntf : ecap;
  float vmax = 0.f;
  for (int e = blockIdx.x * 256 + threadIdx.x; e < n; e += gridDim.x * 256) {
    int s2 = nid[srcf[e]], d2 = nid[dstf[e]];
    if (s2 == d2) continue;
    float ics = 1.f / fmaxf(cnt[s2], 1.f), icd = 1.f / fmaxf(cnt[d2], 1.f);
    vmax = fmaxf(vmax, fabsf(possum[s2*3]   * ics - possum[d2*3]   * icd));
    vmax = fmaxf(vmax, fabsf(possum[s2*3+1] * ics - possum[d2*3+1] * icd));
    vmax = fmaxf(vmax, fabsf(possum[s2*3+2] * ics - possum[d2*3+2] * icd));
    unsigned key = (unsigned)s2 * (unsigned)Nn + (unsigned)d2;
    unsigned bit = 1u << (key & 31);
    unsigned old = atomicOr(&bitmap[key >> 5], bit);
    if (!(old & bit)) {
      int q = atomicAdd(ecntc, 1);
      srcc[q] = s2; dstc[q] = d2;
      nextc[q] = atomicExch(&headc[d2], q + 1);
    }
  }
  #pragma unroll
  for (int off = 32; off; off >>= 1) vmax = fmaxf(vmax, __shfl_down(vmax, off, 64));
  if ((threadIdx.x & 63) == 0) red[threadIdx.x >> 6] = vmax;
  __syncthreads();
  if (threadIdx.x == 0)
    atomicMax((unsigned*)mo,
              __float_as_uint(fmaxf(fmaxf(red[0], red[1]), fmaxf(red[2], red[3]))));
}

// ---------- k_gather: walk list, read pooled x/pos inline, emit bf16 hi/lo ----------
__global__ __launch_bounds__(256)
void k_gather(const float* __restrict__ possum, const float* __restrict__ cnt,
              const unsigned* __restrict__ pordc,
              const int* __restrict__ srcarr, const int* __restrict__ head,
              const int* __restrict__ nextl, const float* __restrict__ mbuf,
              unsigned short* __restrict__ ysh, unsigned short* __restrict__ ysl,
              int N, int Ci, int nchunk) {
  int wid = blockIdx.x * 4 + (threadIdx.x >> 6);
  int lane = threadIdx.x & 63;
  int d = wid / nchunk, ch = wid % nchunk;
  if (d >= N) return;
  int co = ch * 64 + lane;
  float inv = 0.5f / fmaxf(mbuf[0], 1e-9f);
  float cd = cnt[d];
  float icd = 1.f / fmaxf(cd, 1.f);
  float pd0 = possum[d*3] * icd, pd1 = possum[d*3+1] * icd, pd2 = possum[d*3+2] * icd;
  float acc[8] = {};
  int len = 0;
  for (int j = head[d]; j; ) {
    int e = j - 1; j = nextl[e];
    int s = srcarr[e];
    float ics = 1.f / fmaxf(cnt[s], 1.f);
    float u0 = (possum[s*3]   * ics - pd0) * inv + 0.5f;
    float u1 = (possum[s*3+1] * ics - pd1) * inv + 0.5f;
    float u2 = (possum[s*3+2] * ics - pd2) * inv + 0.5f;
    float w[8]; basis8(u0, u1, u2, w);
    float xv = ord2f(pordc[(long)s * Ci + co]);   // edge endpoints always occupied
    #pragma unroll
    for (int k = 0; k < 8; k++) acc[k] += w[k] * xv;
    len++;
  }
  float sc = 1.f / fmaxf((float)len, 1.f);
  long row = (long)d * 9 * Ci;
  #pragma unroll
  for (int k = 0; k < 8; k++) {
    float v = acc[k] * sc;
    unsigned short hu = f2b(v);
    ysh[row + k * Ci + co] = hu;
    ysl[row + k * Ci + co] = f2b(v - b2f(hu));
  }
  float xd = (cd > 0.f) ? ord2f(pordc[(long)d * Ci + co]) : 0.f;
  unsigned short hu = f2b(xd);
  ysh[row + 8 * Ci + co] = hu;
  ysl[row + 8 * Ci + co] = f2b(xd - b2f(hu));
}

// ---------- k_gemmpool: MFMA GEMM + bias + ELU + voxel-pool epilogue ----------
__global__ __launch_bounds__(256)
void k_gemmpool(const unsigned short* __restrict__ ysh, const unsigned short* __restrict__ ysl,
                const unsigned short* __restrict__ Bh, const unsigned short* __restrict__ Bl,
                int M, int N, int K, const float* __restrict__ bias,
                const float* __restrict__ possum, const float* __restrict__ cnt,
                int div, float vs, int G, int NC,
                unsigned* __restrict__ pordn, float* __restrict__ cntn,
                float* __restrict__ possumn, int* __restrict__ nid) {
  __shared__ __align__(16) char smem[20480];
  int nbx = N >> 6;
  int bx = blockIdx.x % nbx, by = blockIdx.x / nbx;
  int m0 = by * 64, n0 = bx * 64;
  f32x4 acc[4] = {};
  mfma_tile(ysh, ysl, Bh, Bl, M, K, m0, n0, 0, K, smem, acc);
  int w = threadIdx.x >> 6, lane = threadIdx.x & 63;
  int row0 = m0 + (w << 4) + ((lane >> 4) << 2);
  int colb = n0 + (lane & 15);
  #pragma unroll
  for (int q = 0; q < 4; q++) {
    int gm = row0 + q;
    float c = cnt[gm];
    float ic = 1.f / fmaxf(c, 1.f);
    float p0 = possum[gm*3] * ic, p1 = possum[gm*3+1] * ic, p2 = possum[gm*3+2] * ic;
    int c0 = clampi((int)floorf(p0 / vs), 0, G - 1);
    int c1 = clampi((int)floorf(p1 / vs), 0, G - 1);
    int c2 = clampi((int)floorf(p2 / vs), 0, G - 1);
    int id = (gm / div) * NC + (c0 * G + c1) * G + c2;
    bool vl = c > 0.f;
    if (bx == 0 && (lane & 15) == 0) {
      nid[gm] = id;
      if (vl) {
        atomicAdd(&cntn[id], 1.f);
        atomicAdd(&possumn[id*3],   p0);
        atomicAdd(&possumn[id*3+1], p1);
        atomicAdd(&possumn[id*3+2], p2);
      }
    }
    if (vl) {
      #pragma unroll
      for (int nt = 0; nt < 4; nt++) {
        int col = colb + nt * 16;
        float v = eluf(acc[nt][q] + bias[col]);
        atomicMax(&pordn[(long)id * N + col], f2ord(v));
      }
    }
  }
}

// ---------- k_gemm4: layer-4 split-K z=4 partials ----------
__global__ __launch_bounds__(256)
void k_gemm4(const unsigned short* __restrict__ ysh, const unsigned short* __restrict__ ysl,
             const unsigned short* __restrict__ Bh, const unsigned short* __restrict__ Bl,
             float* __restrict__ Cp) {
  __shared__ __align__(16) char smem[20480];
  int z = blockIdx.x >> 6, rem = blockIdx.x & 63, bx = rem & 7, by = rem >> 3;
  int m0 = by * 64, n0 = bx * 64;
  f32x4 acc[4] = {};
  mfma_tile(ysh, ysl, Bh, Bl, 500, 2304, m0, n0, z * 576, 576, smem, acc);
  float* Co = Cp + (long)z * 256000;
  int w = threadIdx.x >> 6, lane = threadIdx.x & 63;
  int row0 = m0 + (w << 4) + ((lane >> 4) << 2);
  int colb = n0 + (lane & 15);
  #pragma unroll
  for (int nt = 0; nt < 4; nt++)
    #pragma unroll
    for (int q = 0; q < 4; q++) {
      int gm = row0 + q;
      if (gm < 500) Co[(long)gm * 512 + colb + nt * 16] = acc[nt][q];
    }
}

// ---------- k_reduce4: sum partials + bias + ELU + final MaxPoolingX ----------
__global__ void k_reduce4(const float* __restrict__ Cp, const float* __restrict__ b4,
                          const float* __restrict__ possum3, const float* __restrict__ cnt3,
                          unsigned* __restrict__ xg) {
  int idx = blockIdx.x * 256 + threadIdx.x;
  if (idx >= 256000) return;
  int n = idx >> 9, o = idx & 511;
  float s = Cp[idx] + Cp[idx + 256000] + Cp[idx + 512000] + Cp[idx + 768000];
  float v = eluf(s + b4[o]);
  float c = cnt3[n];
  if (c <= 0.f) return;
  float ic = 1.f / c;
  float p0 = possum3[n*3] * ic, p1 = possum3[n*3+1] * ic, p2 = possum3[n*3+2] * ic;
  int c0 = clampi((int)floorf(p0 / 80.f), 0, 2);
  int c1 = clampi((int)floorf(p1 / 80.f), 0, 2);
  int c2 = clampi((int)floorf(p2 / 80.f), 0, 2);
  int cl = (n / 125) * 64 + (c0 * 3 + c1) * 3 + c2;
  atomicMax(&xg[(long)cl * 512 + o], f2ord(v));
}

// ---------- FC1 (skips the 37/64 always-empty cells) ----------
__global__ __launch_bounds__(128)
void k_fc1(const unsigned* __restrict__ xg_ord, const float* __restrict__ w,
           float* __restrict__ h) {
  int cellhalf = blockIdx.x >> 3, jb = blockIdx.x & 7;
  int cell = cellhalf >> 1, half = cellhalf & 1;
  int j = jb * 128 + threadIdx.x;
  __shared__ float xs[4][256];
  for (int q = threadIdx.x; q < 1024; q += 128) {
    int b = q >> 8, ci = q & 255;
    unsigned o = xg_ord[((b * 64 + cell) << 9) + half * 256 + ci];
    xs[b][ci] = (o == 0u) ? 0.f : ord2f(o);
  }
  __syncthreads();
  float a0 = 0, a1 = 0, a2 = 0, a3 = 0;
  int cbase = cell * 512 + half * 256;
  for (int ci = 0; ci < 256; ci++) {
    float ww = w[(long)(cbase + ci) * 1024 + j];
    a0 += xs[0][ci] * ww; a1 += xs[1][ci] * ww;
    a2 += xs[2][ci] * ww; a3 += xs[3][ci] * ww;
  }
  atomicAdd(&h[j], a0);        atomicAdd(&h[1024 + j], a1);
  atomicAdd(&h[2048 + j], a2); atomicAdd(&h[3072 + j], a3);
}

// ---------- FC2 (fc1 bias+ELU fused) ----------
__global__ void k_fc2(const float* __restrict__ h, const float* __restrict__ fb1,
                      const float* __restrict__ w, const float* __restrict__ b,
                      float* __restrict__ out) {
  int bb = blockIdx.x, t = threadIdx.x;
  float a = 0;
  for (int j = t; j < 1024; j += 256) a += eluf(h[bb * 1024 + j] + fb1[j]) * w[j];
  for (int off = 32; off; off >>= 1) a += __shfl_down(a, off, 64);
  __shared__ float red[4];
  int lane = t & 63, wv = t >> 6;
  if (lane == 0) red[wv] = a;
  __syncthreads();
  if (t == 0) out[bb] = eluf(red[0] + red[1] + red[2] + red[3] + b[0]);
}

// =======================================================================
extern "C" void kernel_launch(void* const* d_in, const int* in_sizes, int n_in,
                              void* d_out, int out_size, void* d_ws, size_t ws_size,
                              hipStream_t stream) {
  const float* x0   = (const float*)d_in[0];
  const float* pos0 = (const float*)d_in[1];
  const int*   ei   = (const int*)d_in[2];
  const float* W1 = (const float*)d_in[4],  *Wr1 = (const float*)d_in[5],  *b1 = (const float*)d_in[6];
  const float* W2 = (const float*)d_in[7],  *Wr2 = (const float*)d_in[8],  *b2 = (const float*)d_in[9];
  const float* W3 = (const float*)d_in[10], *Wr3 = (const float*)d_in[11], *b3 = (const float*)d_in[12];
  const float* W4 = (const float*)d_in[13], *Wr4 = (const float*)d_in[14], *b4 = (const float*)d_in[15];
  const float* fw1 = (const float*)d_in[16], *fb1 = (const float*)d_in[17];
  const float* fw2 = (const float*)d_in[18], *fb2 = (const float*)d_in[19];
  float* out = (float*)d_out;
  const int* src0 = ei;
  const int* dst0 = ei + E0;

  char* ws = (char*)d_ws;
  size_t off = 0;
  auto alloc = [&](size_t bytes) -> void* {
    off = (off + 255) & ~(size_t)255;
    void* q = ws + off; off += bytes; return q;
  };
  // non-zeroed buffers
  int* next0 = (int*)alloc(E0 * 4);
  int* src1 = (int*)alloc(E0 * 4); int* dst1 = (int*)alloc(E0 * 4); int* next1 = (int*)alloc(E0 * 4);
  int* src2 = (int*)alloc(E0 * 4); int* dst2 = (int*)alloc(E0 * 4); int* next2 = (int*)alloc(E0 * 4);
  int* src3 = (int*)alloc(E0 * 4); int* dst3 = (int*)alloc(E0 * 4); int* next3 = (int*)alloc(E0 * 4);
  int* nid  = (int*)alloc(NL0 * 4);
  unsigned short* ysh = (unsigned short*)alloc((size_t)NL1 * 576 * 2);
  unsigned short* ysl = (unsigned short*)alloc((size_t)NL1 * 576 * 2);
  float* wc1 = (float*)alloc(576 * 4);
  unsigned short* w2h = (unsigned short*)alloc((size_t)576 * 128 * 2);
  unsigned short* w2l = (unsigned short*)alloc((size_t)576 * 128 * 2);
  unsigned short* w3h = (unsigned short*)alloc((size_t)1152 * 256 * 2);
  unsigned short* w3l = (unsigned short*)alloc((size_t)1152 * 256 * 2);
  unsigned short* w4h = (unsigned short*)alloc((size_t)2304 * 512 * 2);
  unsigned short* w4l = (unsigned short*)alloc((size_t)2304 * 512 * 2);
  float* Cp = (float*)alloc((size_t)4 * 256000 * 4);
  // zero region (single memset per call)
  char* z0 = (char*)alloc(0);
  int* head0 = (int*)alloc(NL0 * 4);
  int* head1 = (int*)alloc(NL1 * 4);
  int* head2 = (int*)alloc(NL2 * 4);
  int* head3 = (int*)alloc(NL3 * 4);
  unsigned* pord1 = (unsigned*)alloc((size_t)NL1 * 64 * 4);
  unsigned* pord2 = (unsigned*)alloc((size_t)NL2 * 128 * 4);
  unsigned* pord3 = (unsigned*)alloc((size_t)NL3 * 256 * 4);
  unsigned* xg    = (unsigned*)alloc((size_t)4 * 64 * 512 * 4);
  float* cnt1 = (float*)alloc(NL1 * 4);
  float* cnt2 = (float*)alloc(NL2 * 4);
  float* cnt3 = (float*)alloc(NL3 * 4);
  float* possum1 = (float*)alloc(NL1 * 12);
  float* possum2 = (float*)alloc(NL2 * 12);
  float* possum3 = (float*)alloc(NL3 * 12);
  size_t bm1w = ((size_t)NL1 * NL1 + 31) / 32;
  size_t bm2w = ((size_t)NL2 * NL2 + 31) / 32;
  size_t bm3w = ((size_t)NL3 * NL3 + 31) / 32;
  unsigned* bm1 = (unsigned*)alloc(bm1w * 4);
  unsigned* bm2 = (unsigned*)alloc(bm2w * 4);
  unsigned* bm3 = (unsigned*)alloc(bm3w * 4);
  float* mbuf = (float*)alloc(64);
  int* ecnt = (int*)(mbuf + 8);
  float* h = (float*)alloc(4096 * 4);
  char* zend = (char*)alloc(0);
  size_t zbytes = (size_t)(zend - z0);
  (void)ws_size; (void)in_sizes; (void)n_in; (void)out_size;

  auto cdiv = [](long a, long b) { return (int)((a + b - 1) / b); };

  hipMemsetAsync(z0, 0, zbytes, stream);

  // L0: list build + absmax + weight prep
  k_prep<<<512, 256, 0, stream>>>(src0, dst0, pos0, head0, next0, mbuf,
                                  W1, Wr1, wc1, W2, Wr2, W3, Wr3, W4, Wr4,
                                  w2h, w2l, w3h, w3l, w4h, w4l);
  // layer 1 + pool 1
  k_l1<<<cdiv(NL0, 4), 256, 0, stream>>>(pos0, x0, src0, head0, next0, mbuf,
                                         wc1, b1, pord1, cnt1, possum1, nid);
  k_pedge<<<512, 256, 0, stream>>>(src0, dst0, nullptr, E0, nid, NL1, bm1,
                                   src1, dst1, next1, head1, ecnt + 0,
                                   possum1, cnt1, mbuf + 1);
  // layer 2 + pool 2
  k_gather<<<cdiv(NL1, 4), 256, 0, stream>>>(possum1, cnt1, pord1, src1, head1, next1,
                                             mbuf + 1, ysh, ysl, NL1, 64, 1);
  k_gemmpool<<<(128 / 64) * (NL1 / 64), 256, 0, stream>>>(
      ysh, ysl, w2h, w2l, NL1, 128, 576, b2, possum1, cnt1,
      1728, 30.f, 8, 512, pord2, cnt2, possum2, nid);
  k_pedge<<<512, 256, 0, stream>>>(src1, dst1, ecnt + 0, E0, nid, NL2, bm2,
                                   src2, dst2, next2, head2, ecnt + 1,
                                   possum2, cnt2, mbuf + 2);
  // layer 3 + pool 3
  k_gather<<<cdiv(NL2 * 2, 4), 256, 0, stream>>>(possum2, cnt2, pord2, src2, head2, next2,
                                                 mbuf + 2, ysh, ysl, NL2, 128, 2);
  k_gemmpool<<<(256 / 64) * (NL2 / 64), 256, 0, stream>>>(
      ysh, ysl, w3h, w3l, NL2, 256, 1152, b3, possum2, cnt2,
      512, 50.f, 5, 125, pord3, cnt3, possum3, nid);
  k_pedge<<<512, 256, 0, stream>>>(src2, dst2, ecnt + 1, E0, nid, NL3, bm3,
                                   src3, dst3, next3, head3, ecnt + 2,
                                   possum3, cnt3, mbuf + 3);
  // layer 4 + final pool
  k_gather<<<cdiv(NL3 * 4, 4), 256, 0, stream>>>(possum3, cnt3, pord3, src3, head3, next3,
                                                 mbuf + 3, ysh, ysl, NL3, 256, 4);
  k_gemm4<<<256, 256, 0, stream>>>(ysh, ysl, w4h, w4l, Cp);
  k_reduce4<<<cdiv(256000, 256), 256, 0, stream>>>(Cp, b4, possum3, cnt3, xg);
  // FC head
  k_fc1<<<27 * 2 * 8, 128, 0, stream>>>(xg, fw1, h);
  k_fc2<<<4, 256, 0, stream>>>(h, fb1, fw2, fb2, out);
}